// Round 1
// baseline (410.087 us; speedup 1.0000x reference)
//
#include <hip/hip_runtime.h>
#include <cstdint>
#include <cstddef>

typedef unsigned int u32;
typedef unsigned short u16;
typedef uint8_t u8;

// Problem constants
constexpr int kNB = 2, kL = 3000, kS = 3000, kC = 256, kH = 256, kFC = 8, kD = 32;
constexpr int kTP = 3008;   // padded T (rows) for q/vT/m_h  (47*64)
constexpr int kSP = 3008;   // padded mask row stride (bytes)
constexpr int kTB = 40;     // LDS row stride (elements) -> 80B: keeps b128 16B-aligned, ~2-way banks
constexpr float kQSC = 0.4204482076268573f;  // 32^(-1/4); applied to BOTH q sides -> sim * 1/sqrt(32)

typedef __attribute__((ext_vector_type(8))) short short8;
typedef __attribute__((ext_vector_type(4))) float f32x4;

__device__ __forceinline__ u16 f2bf(float f) {          // RNE
  u32 u = __float_as_uint(f);
  u += 0x7FFFu + ((u >> 16) & 1u);
  return (u16)(u >> 16);
}
__device__ __forceinline__ float bf2f(u16 h) { return __uint_as_float(((u32)h) << 16); }
__device__ __forceinline__ f32x4 mfma16(short8 a, short8 b, f32x4 c) {
  return __builtin_amdgcn_mfma_f32_16x16x32_bf16(a, b, c, 0, 0, 0);
}

// ---------------- workspace layout (bytes) ----------------
constexpr size_t SZ_Q   = (size_t)kNB * kFC * kTP * kD * 2;  // 3,080,192
constexpr size_t SZ_MH  = (size_t)kNB * kTP * kH * 2;        // 3,080,192
constexpr size_t OFF_Q0 = 256;
constexpr size_t OFF_Q1 = OFF_Q0 + SZ_Q;
constexpr size_t OFF_V0 = OFF_Q1 + SZ_Q;
constexpr size_t OFF_V1 = OFF_V0 + SZ_Q;
constexpr size_t OFF_M0 = OFF_V1 + SZ_Q;
constexpr size_t OFF_M1 = OFF_M0 + SZ_MH;
constexpr size_t OFF_WT = OFF_M1 + SZ_MH;                    // WT_proj [512][256] bf16
constexpr size_t OFF_WM = OFF_WT + (size_t)2 * kH * kC * 2;  // WmT [256][256] bf16
constexpr size_t OFF_MK = OFF_WM + (size_t)kC * kH * 2;      // mask_u8 [n][L][SP]
constexpr size_t SZ_MK  = (size_t)kNB * kL * kSP;            // 18,048,000
constexpr size_t OFF_MKT = OFF_MK + SZ_MK;                   // maskT_u8 [n][S][SP]

// ---------------- K0: dtype detection (deterministic, every call) ----------------
// flag[0]: mask dtype  0=u8 1=bf16 2=i32 3=f32 4=f16
// flag[1]: float dtype 0=bf16 1=f32
__global__ __launch_bounds__(256) void k_detect(const u8* __restrict__ mraw,
                                                const u8* __restrict__ xraw,
                                                u32* __restrict__ flag) {
  __shared__ int c1[4], c3f[4], c3c, cexp;
  int tid = threadIdx.x;
  if (tid < 4) { c1[tid] = 0; c3f[tid] = 0; }
  if (tid == 0) { c3c = 0; cexp = 0; }
  __syncthreads();
  int l1[4] = {0,0,0,0}, l3f[4] = {0,0,0,0}, l3c = 0, lex = 0;
  for (int j = 0; j < 16; ++j) {
    int i = tid * 16 + j;
    u8 b = mraw[i];
    int r = i & 3;
    l1[r]  += (b == 1);
    l3f[r] += (b == 0x3F);
    if (i & 1) l3c += (b == 0x3C);
    if (r == 1) { u32 v = xraw[i] & 0x7F; lex += (v >= 0x3E && v <= 0x40); }
  }
  for (int r = 0; r < 4; ++r) {
    if (l1[r])  atomicAdd(&c1[r], l1[r]);
    if (l3f[r]) atomicAdd(&c3f[r], l3f[r]);
  }
  if (l3c) atomicAdd(&c3c, l3c);
  if (lex) atomicAdd(&cexp, lex);
  __syncthreads();
  if (tid == 0) {
    u32 mf;
    if (c1[1] + c1[2] + c1[3] > 64) mf = 0;       // u8/bool bytes
    else if (c1[0] > 64)            mf = 2;       // i32
    else if (c3f[1] > 64)           mf = 1;       // bf16 (0x3F at odd bytes)
    else if (c3c > 64)              mf = 4;       // f16
    else                            mf = 3;       // f32
    flag[0] = mf;
    flag[1] = (cexp > 300) ? 0u : 1u;             // bf16 high-byte signature on x0
  }
}

// ---------------- K1: mask normalize + transpose -> u8 [row][SP] ----------------
__global__ __launch_bounds__(256) void k_masknorm(const void* __restrict__ mraw,
                                                  const u32* __restrict__ flag,
                                                  u8* __restrict__ mk, u8* __restrict__ mkt) {
  u32 mf = flag[0];
  int n = blockIdx.z, l0 = blockIdx.x * 64, s0 = blockIdx.y * 64;
  __shared__ u8 tile[64][65];
  int tid = threadIdx.x;
  for (int k = 0; k < 16; ++k) {
    int e = tid + 256 * k;
    int row = e >> 6, col = e & 63;
    int l = l0 + row, s = s0 + col;
    u32 v = 0;
    if (l < kL && s < kS) {
      size_t idx = ((size_t)n * kL + l) * kS + s;
      if (mf == 0)      v = ((const u8*)mraw)[idx];
      else if (mf == 1 || mf == 4) v = ((const u16*)mraw)[idx];
      else              v = ((const u32*)mraw)[idx];
      v = v ? 1u : 0u;
      mk[((size_t)n * kL + l) * kSP + s] = (u8)v;
    }
    tile[row][col] = (u8)v;
  }
  __syncthreads();
  for (int k = 0; k < 16; ++k) {
    int e = tid + 256 * k;
    int row = e >> 6, col = e & 63;     // row -> s, col -> l
    int s = s0 + row, l = l0 + col;
    if (s < kS && l < kL) mkt[((size_t)n * kS + s) * kSP + l] = tile[col][row];
  }
}

// ---------------- K1b: transpose weights to [col][k] bf16 ----------------
__global__ __launch_bounds__(256) void k_wtrans(const void* __restrict__ Wp,
                                                const void* __restrict__ Wm,
                                                const u32* __restrict__ flag,
                                                u16* __restrict__ WT, u16* __restrict__ WmT) {
  u32 f2 = flag[1];
  int b = blockIdx.x, k = threadIdx.x;
  if (b < 2 * kH) {
    int col = b;
    u16 v = (f2 == 0) ? ((const u16*)Wp)[(size_t)k * (2 * kH) + col]
                      : f2bf(((const float*)Wp)[(size_t)k * (2 * kH) + col]);
    WT[(size_t)col * kC + k] = v;
  } else {
    int col = b - 2 * kH;
    u16 v = (f2 == 0) ? ((const u16*)Wm)[(size_t)k * kC + col]
                      : f2bf(((const float*)Wm)[(size_t)k * kC + col]);
    WmT[(size_t)col * kH + k] = v;
  }
}

// ---------------- K2: projection GEMM -> q (scaled), vT ----------------
__global__ __launch_bounds__(256) void k_proj(const void* __restrict__ x0,
                                              const void* __restrict__ x1,
                                              const u16* __restrict__ WT,
                                              const void* __restrict__ bias,
                                              const u32* __restrict__ flag,
                                              u16* __restrict__ q0, u16* __restrict__ v0t,
                                              u16* __restrict__ q1, u16* __restrict__ v1t) {
  u32 f2 = flag[1];
  int z = blockIdx.z;
  const void* X = z ? x1 : x0;
  u16* Q = z ? q1 : q0;
  u16* V = z ? v1t : v0t;
  int tid = threadIdx.x, w = tid >> 6, lane = tid & 63, quad = lane >> 4, c16 = lane & 15;
  int r0 = blockIdx.x * 16;
  int c  = blockIdx.y * 64 + w * 16 + c16;
  f32x4 acc = {0.f, 0.f, 0.f, 0.f};
#pragma unroll
  for (int k0 = 0; k0 < kC; k0 += 32) {
    short8 a;
    if (f2 == 0) {
      a = *(const short8*)((const u16*)X + (size_t)(r0 + c16) * kC + k0 + quad * 8);
    } else {
      const float* Xf = (const float*)X + (size_t)(r0 + c16) * kC + k0 + quad * 8;
#pragma unroll
      for (int j = 0; j < 8; ++j) a[j] = (short)f2bf(Xf[j]);
    }
    short8 b = *(const short8*)(WT + (size_t)c * kC + k0 + quad * 8);
    acc = mfma16(a, b, acc);
  }
  float bb = (f2 == 0) ? bf2f(((const u16*)bias)[c]) : ((const float*)bias)[c];
#pragma unroll
  for (int r = 0; r < 4; ++r) {
    int row = r0 + quad * 4 + r;       // flat over (n,t), 0..5999
    int n = (row >= kL) ? 1 : 0;
    int t = row - n * kL;
    float val = acc[r] + bb;
    if (c < kH) {                      // qk half
      val *= kQSC;
      int ff = c >> 5, d = c & 31;
      Q[((size_t)(n * kFC + ff) * kTP + t) * kD + d] = f2bf(val);
    } else {                           // v half -> transposed [d][t]
      int cc = c - kH;
      int ff = cc >> 5, d = cc & 31;
      V[((size_t)(n * kFC + ff) * kD + d) * kTP + t] = f2bf(val);
    }
  }
}

// ---------------- K3: bidirectional flash attention (z = direction) ----------------
__global__ __launch_bounds__(256) void k_flash(const u16* __restrict__ q0,
                                               const u16* __restrict__ q1,
                                               const u16* __restrict__ v0t,
                                               const u16* __restrict__ v1t,
                                               const u8* __restrict__ mk,
                                               const u8* __restrict__ mkt,
                                               u16* __restrict__ m0h, u16* __restrict__ m1h) {
  const int z = blockIdx.z;
  const u16* QA = z ? q1 : q0;   // rows (softmax output rows)
  const u16* QB = z ? q0 : q1;   // swept side
  const u16* VT = z ? v0t : v1t; // values, transposed [d][t]
  const u8*  MK = z ? mkt : mk;  // [row][SP]
  u16* MO = z ? m1h : m0h;

  const int nf = blockIdx.y;
  const int n = nf >> 3, f = nf & 7;
  const int tid = threadIdx.x, w = tid >> 6, lane = tid & 63;
  const int quad = lane >> 4, c16 = lane & 15;

  __align__(16) __shared__ u16 lds_qb[32 * kTB];
  __align__(16) __shared__ u16 lds_vt[32 * kTB];
  __align__(16) __shared__ u16 lds_P[4 * 16 * kTB];
  __align__(16) __shared__ u8  lds_mk[64 * 32];

  const u16* qa_nf = QA + (size_t)(n * kFC + f) * kTP * kD;
  const u16* qb_nf = QB + (size_t)(n * kFC + f) * kTP * kD;
  const u16* vt_nf = VT + (size_t)(n * kFC + f) * kD * kTP;
  const u8*  mk_n  = MK + (size_t)n * kL * kSP;

  const int l0 = blockIdx.x * 64;
  const int lw = l0 + w * 16;

  // constant A-fragment: qa rows [lw + c16], k = d (padded alloc makes OOB reads safe zeros)
  short8 afrag = *(const short8*)(qa_nf + (size_t)(lw + c16) * kD + quad * 8);
  short8 bones;
#pragma unroll
  for (int i = 0; i < 8; ++i) bones[i] = (short)0x3F80;  // bf16 1.0

  f32x4 acc0 = {0.f,0.f,0.f,0.f}, acc1 = {0.f,0.f,0.f,0.f}, accs = {0.f,0.f,0.f,0.f};

  const int st_a = tid >> 3;          // 0..31
  const int st_b = (tid & 7) * 4;     // 0,4,...,28
  const int mr = tid >> 2;            // 0..63
  const int mc = (tid & 3) * 8;       // 0,8,16,24
  int mrow = l0 + mr; if (mrow >= kL) mrow = kL - 1;

  u16* Pl = lds_P + w * 16 * kTB;

  for (int j0 = 0; j0 < kS; j0 += 32) {
    __syncthreads();
    // stage qb chunk [32 s][32 d] (contiguous 2KB)
    {
      uint2 v = *(const uint2*)(qb_nf + (size_t)(j0 + st_a) * kD + st_b);
      *(uint2*)(lds_qb + st_a * kTB + st_b) = v;
    }
    // stage vT chunk [32 d][32 s]
    {
      uint2 v = *(const uint2*)(vt_nf + (size_t)st_a * kTP + j0 + st_b);
      *(uint2*)(lds_vt + st_a * kTB + st_b) = v;
    }
    // stage mask chunk [64 rows][32 cols]
    {
      uint2 v = *(const uint2*)(mk_n + (size_t)mrow * kSP + j0 + mc);
      *(uint2*)(lds_mk + mr * 32 + mc) = v;
    }
    __syncthreads();

    float P[2][4];
#pragma unroll
    for (int t = 0; t < 2; ++t) {
      short8 bq = *(const short8*)(lds_qb + (t * 16 + c16) * kTB + quad * 8);
      f32x4 zero = {0.f,0.f,0.f,0.f};
      f32x4 sim = mfma16(afrag, bq, zero);
      bool colok = (j0 + t * 16 + c16) < kS;
#pragma unroll
      for (int r = 0; r < 4; ++r) {
        u8 mb = lds_mk[(w * 16 + quad * 4 + r) * 32 + t * 16 + c16];
        float p = __expf(sim[r]);                  // logits bounded (~|8|), no max needed
        P[t][r] = (mb && colok) ? p : 0.f;
      }
    }
    // write P (bf16 truncation; bias cancels in num/denom ratio)
#pragma unroll
    for (int t = 0; t < 2; ++t)
#pragma unroll
      for (int r = 0; r < 4; ++r)
        Pl[(quad * 4 + r) * kTB + t * 16 + c16] = (u16)(__float_as_uint(P[t][r]) >> 16);

    // P -> A-frag (wave-private LDS region, no barrier needed)
    short8 ap  = *(const short8*)(Pl + c16 * kTB + quad * 8);
    short8 bv0 = *(const short8*)(lds_vt + (c16) * kTB + quad * 8);
    short8 bv1 = *(const short8*)(lds_vt + (16 + c16) * kTB + quad * 8);
    acc0 = mfma16(ap, bv0, acc0);
    acc1 = mfma16(ap, bv1, acc1);
    accs = mfma16(ap, bones, accs);   // row-sum via ones-MFMA (all lanes get row sum)
  }

#pragma unroll
  for (int r = 0; r < 4; ++r) {
    float ls = accs[r];
    float rd = (ls > 0.f) ? (1.f / ls) : 0.f;
    int lrow = lw + quad * 4 + r;
    if (lrow < kL) {
      size_t base = ((size_t)n * kTP + lrow) * kH + f * kD;
      MO[base + c16]      = f2bf(acc0[r] * rd);
      MO[base + 16 + c16] = f2bf(acc1[r] * rd);
    }
  }
}

// ---------------- K5: merge GEMM + bias -> output ----------------
__global__ __launch_bounds__(256) void k_merge(const u16* __restrict__ m0h,
                                               const u16* __restrict__ m1h,
                                               const u16* __restrict__ WmT,
                                               const void* __restrict__ bias,
                                               const u32* __restrict__ flag,
                                               void* __restrict__ out) {
  u32 f2 = flag[1];
  int z = blockIdx.z;
  const u16* A = z ? m1h : m0h;
  int tid = threadIdx.x, w = tid >> 6, lane = tid & 63, quad = lane >> 4, c16 = lane & 15;
  int r0 = blockIdx.x * 16;                     // rows flat over [n][TP], 0..6015
  int c  = blockIdx.y * 64 + w * 16 + c16;      // 0..255
  f32x4 acc = {0.f,0.f,0.f,0.f};
#pragma unroll
  for (int k0 = 0; k0 < kH; k0 += 32) {
    short8 a = *(const short8*)(A + (size_t)(r0 + c16) * kH + k0 + quad * 8);
    short8 b = *(const short8*)(WmT + (size_t)c * kH + k0 + quad * 8);
    acc = mfma16(a, b, acc);
  }
  float bb = (f2 == 0) ? bf2f(((const u16*)bias)[c]) : ((const float*)bias)[c];
  size_t obase = (size_t)z * ((size_t)kNB * kL * kC);
#pragma unroll
  for (int r = 0; r < 4; ++r) {
    int row = r0 + quad * 4 + r;
    int n = (row >= kTP) ? 1 : 0;
    int t = row - n * kTP;
    if (t < kL) {
      size_t oi = obase + ((size_t)n * kL + t) * kC + c;
      float v = acc[r] + bb;
      if (f2 == 0) ((u16*)out)[oi] = f2bf(v);
      else         ((float*)out)[oi] = v;
    }
  }
}

// ---------------- host ----------------
extern "C" void kernel_launch(void* const* d_in, const int* in_sizes, int n_in,
                              void* d_out, int out_size, void* d_ws, size_t ws_size,
                              hipStream_t stream) {
  (void)in_sizes; (void)n_in; (void)out_size; (void)ws_size;
  u8* ws = (u8*)d_ws;
  u32* flag = (u32*)ws;
  u16* q0  = (u16*)(ws + OFF_Q0);
  u16* q1  = (u16*)(ws + OFF_Q1);
  u16* v0t = (u16*)(ws + OFF_V0);
  u16* v1t = (u16*)(ws + OFF_V1);
  u16* m0h = (u16*)(ws + OFF_M0);
  u16* m1h = (u16*)(ws + OFF_M1);
  u16* WT  = (u16*)(ws + OFF_WT);
  u16* WmT = (u16*)(ws + OFF_WM);
  u8*  mk  = (u8*)(ws + OFF_MK);
  u8*  mkt = (u8*)(ws + OFF_MKT);

  const void* x0 = d_in[0];
  const void* x1 = d_in[1];
  const void* mraw = d_in[2];
  const void* Wp = d_in[3];
  const void* bp = d_in[4];
  const void* Wm = d_in[5];
  const void* bm = d_in[6];

  // zero q/vT/m_h (covers padded rows so OOB fragment reads are exact zeros)
  hipMemsetAsync(ws + OFF_Q0, 0, 4 * SZ_Q + 2 * SZ_MH, stream);

  k_detect<<<1, 256, 0, stream>>>((const u8*)mraw, (const u8*)x0, flag);
  k_masknorm<<<dim3(47, 47, 2), 256, 0, stream>>>(mraw, flag, mk, mkt);
  k_wtrans<<<dim3(2 * kH + kC), 256, 0, stream>>>(Wp, Wm, flag, WT, WmT);
  k_proj<<<dim3(375, 8, 2), 256, 0, stream>>>(x0, x1, WT, bp, flag, q0, v0t, q1, v1t);
  k_flash<<<dim3(47, 16, 2), 256, 0, stream>>>(q0, q1, v0t, v1t, mk, mkt, m0h, m1h);
  k_merge<<<dim3(376, 4, 2), 256, 0, stream>>>(m0h, m1h, WmT, bm, flag, d_out);
}

// Round 2
// 408.682 us; speedup vs baseline: 1.0034x; 1.0034x over previous
//
#include <hip/hip_runtime.h>
#include <cstdint>
#include <cstddef>

typedef unsigned int u32;
typedef unsigned short u16;
typedef uint8_t u8;
typedef unsigned long long u64;

// Problem constants
constexpr int kNB = 2, kL = 3000, kS = 3000, kC = 256, kH = 256, kFC = 8, kD = 32;
constexpr int kTP = 3008;   // padded rows (47*64)
constexpr int kMW = 48;     // mask bit-words per row (47 used, pad to 48)
constexpr int kPS = 72;     // P LDS row stride (elements)
// 32^(-1/4) * sqrt(log2(e)): applied to BOTH q sides -> sim = logit*log2e, P = exp2(sim)
constexpr float kQSC = 0.5050097568f;

typedef __attribute__((ext_vector_type(8))) short short8;
typedef __attribute__((ext_vector_type(4))) float f32x4;

__device__ __forceinline__ u16 f2bf(float f) {          // RNE
  u32 u = __float_as_uint(f);
  u += 0x7FFFu + ((u >> 16) & 1u);
  return (u16)(u >> 16);
}
__device__ __forceinline__ float bf2f(u16 h) { return __uint_as_float(((u32)h) << 16); }
__device__ __forceinline__ f32x4 mfma16(short8 a, short8 b, f32x4 c) {
  return __builtin_amdgcn_mfma_f32_16x16x32_bf16(a, b, c, 0, 0, 0);
}
__device__ __forceinline__ u32 pk2(float a, float b) {   // truncate-pack two bf16
  return (__float_as_uint(a) >> 16) | (__float_as_uint(b) & 0xFFFF0000u);
}

// ---------------- workspace layout (bytes) ----------------
constexpr size_t SZ_Q   = (size_t)kNB * kFC * kTP * kD * 2;  // 3,080,192
constexpr size_t SZ_MH  = (size_t)kNB * kTP * kH * 2;        // 3,080,192
constexpr size_t SZ_XB  = (size_t)kNB * kL * kC * 2;         // 3,072,000
constexpr size_t SZ_MKB = (size_t)kNB * kTP * kMW * 8;       // 2,310,144
constexpr size_t OFF_Q0 = 256;
constexpr size_t OFF_Q1 = OFF_Q0 + SZ_Q;
constexpr size_t OFF_V0 = OFF_Q1 + SZ_Q;
constexpr size_t OFF_V1 = OFF_V0 + SZ_Q;
constexpr size_t OFF_M0 = OFF_V1 + SZ_Q;
constexpr size_t OFF_M1 = OFF_M0 + SZ_MH;
constexpr size_t OFF_WT = OFF_M1 + SZ_MH;                    // WT_proj [512][256] bf16
constexpr size_t OFF_WM = OFF_WT + (size_t)2 * kH * kC * 2;  // WmT [256][256] bf16
constexpr size_t OFF_X0 = OFF_WM + (size_t)kC * kH * 2;      // xb0 bf16 [6000][256]
constexpr size_t OFF_X1 = OFF_X0 + SZ_XB;
constexpr size_t OFF_MKB  = OFF_X1 + SZ_XB;                  // row-mask bits [n][3008][48] u64
constexpr size_t OFF_MKBT = OFF_MKB + SZ_MKB;                // col-mask bits (transposed)

// ---------------- K0: dtype detection (deterministic, every call) ----------------
// flag[0]: mask dtype 0=u8 1=bf16 2=i32 3=f32 4=f16 ; flag[1]: float dtype 0=bf16 1=f32
__global__ __launch_bounds__(256) void k_detect(const u8* __restrict__ mraw,
                                                const u8* __restrict__ xraw,
                                                u32* __restrict__ flag) {
  __shared__ int c1[4], c3f[4], c3c, cexp;
  int tid = threadIdx.x;
  if (tid < 4) { c1[tid] = 0; c3f[tid] = 0; }
  if (tid == 0) { c3c = 0; cexp = 0; }
  __syncthreads();
  int l1[4] = {0,0,0,0}, l3f[4] = {0,0,0,0}, l3c = 0, lex = 0;
  for (int j = 0; j < 16; ++j) {
    int i = tid * 16 + j;
    u8 b = mraw[i];
    int r = i & 3;
    l1[r]  += (b == 1);
    l3f[r] += (b == 0x3F);
    if (i & 1) l3c += (b == 0x3C);
    if (r == 1) { u32 v = xraw[i] & 0x7F; lex += (v >= 0x3E && v <= 0x40); }
  }
  for (int r = 0; r < 4; ++r) {
    if (l1[r])  atomicAdd(&c1[r], l1[r]);
    if (l3f[r]) atomicAdd(&c3f[r], l3f[r]);
  }
  if (l3c) atomicAdd(&c3c, l3c);
  if (lex) atomicAdd(&cexp, lex);
  __syncthreads();
  if (tid == 0) {
    u32 mf;
    if (c1[1] + c1[2] + c1[3] > 64) mf = 0;
    else if (c1[0] > 64)            mf = 2;
    else if (c3f[1] > 64)           mf = 1;
    else if (c3c > 64)              mf = 4;
    else                            mf = 3;
    flag[0] = mf;
    flag[1] = (cexp > 300) ? 0u : 1u;
  }
}

// ---------------- K1: mask -> bit masks (both orientations) via ballot ----------------
__global__ __launch_bounds__(256) void k_masknorm(const void* __restrict__ mraw,
                                                  const u32* __restrict__ flag,
                                                  u64* __restrict__ mkb,
                                                  u64* __restrict__ mkbt) {
  const u32 mf = flag[0];
  const int n = blockIdx.z;
  const int l0 = blockIdx.x * 64, s0 = blockIdx.y * 64;
  __shared__ u16 tb[64][4];
  const int tid = threadIdx.x;
  {
    const int row = tid >> 2, sg = (tid & 3) * 16;
    const int l = l0 + row;
    u32 bits = 0;
    if (l < kL) {
      const size_t base = ((size_t)n * kL + l) * kS + s0 + sg;
      if (mf == 3) {
        if (s0 + sg + 16 <= kS) {
          const float4* p = (const float4*)(((const float*)mraw) + base);
          float4 a = p[0], b = p[1], c = p[2], d = p[3];
          bits = (u32)(a.x != 0.f)        | ((u32)(a.y != 0.f) << 1)
               | ((u32)(a.z != 0.f) << 2) | ((u32)(a.w != 0.f) << 3)
               | ((u32)(b.x != 0.f) << 4) | ((u32)(b.y != 0.f) << 5)
               | ((u32)(b.z != 0.f) << 6) | ((u32)(b.w != 0.f) << 7)
               | ((u32)(c.x != 0.f) << 8) | ((u32)(c.y != 0.f) << 9)
               | ((u32)(c.z != 0.f) << 10)| ((u32)(c.w != 0.f) << 11)
               | ((u32)(d.x != 0.f) << 12)| ((u32)(d.y != 0.f) << 13)
               | ((u32)(d.z != 0.f) << 14)| ((u32)(d.w != 0.f) << 15);
        } else {
          for (int i = 0; i < 16; ++i)
            if (s0 + sg + i < kS && ((const float*)mraw)[base + i] != 0.f) bits |= 1u << i;
        }
      } else if (mf == 0) {
        for (int i = 0; i < 16; ++i)
          if (s0 + sg + i < kS && ((const u8*)mraw)[base + i]) bits |= 1u << i;
      } else if (mf == 1 || mf == 4) {
        for (int i = 0; i < 16; ++i)
          if (s0 + sg + i < kS && ((const u16*)mraw)[base + i]) bits |= 1u << i;
      } else {
        for (int i = 0; i < 16; ++i)
          if (s0 + sg + i < kS && ((const u32*)mraw)[base + i]) bits |= 1u << i;
      }
    }
    tb[row][tid & 3] = (u16)bits;
  }
  __syncthreads();
  const int w = tid >> 6, lane = tid & 63;
  for (int k = 0; k < 16; ++k) {
    const int ro = w * 16 + k;
    u32 b1 = (tb[ro][lane >> 4] >> (lane & 15)) & 1;   // row l0+ro, bit s = lane
    u64 word = __ballot((int)b1);
    if (lane == 0) mkb[((size_t)n * kTP + l0 + ro) * kMW + (s0 >> 6)] = word;
    u32 b2 = (tb[lane][ro >> 4] >> (ro & 15)) & 1;     // row s0+ro, bit l = lane
    u64 wordt = __ballot((int)b2);
    if (lane == 0) mkbt[((size_t)n * kTP + s0 + ro) * kMW + (l0 >> 6)] = wordt;
  }
}

// ---------------- K1b: transpose weights to [col][k] bf16 ----------------
__global__ __launch_bounds__(256) void k_wtrans(const void* __restrict__ Wp,
                                                const void* __restrict__ Wm,
                                                const u32* __restrict__ flag,
                                                u16* __restrict__ WT, u16* __restrict__ WmT) {
  u32 f2 = flag[1];
  int b = blockIdx.x, k = threadIdx.x;
  if (b < 2 * kH) {
    int col = b;
    u16 v = (f2 == 0) ? ((const u16*)Wp)[(size_t)k * (2 * kH) + col]
                      : f2bf(((const float*)Wp)[(size_t)k * (2 * kH) + col]);
    WT[(size_t)col * kC + k] = v;
  } else {
    int col = b - 2 * kH;
    u16 v = (f2 == 0) ? ((const u16*)Wm)[(size_t)k * kC + col]
                      : f2bf(((const float*)Wm)[(size_t)k * kC + col]);
    WmT[(size_t)col * kH + k] = v;
  }
}

// ---------------- K1c: cast x to bf16 (or copy) ----------------
__global__ __launch_bounds__(256) void k_cvtx(const void* __restrict__ x0,
                                              const void* __restrict__ x1,
                                              const u32* __restrict__ flag,
                                              u16* __restrict__ xb0, u16* __restrict__ xb1) {
  u32 f2 = flag[1];
  const void* X = blockIdx.y ? x1 : x0;
  u16* B = blockIdx.y ? xb1 : xb0;
  int i = blockIdx.x * 256 + threadIdx.x;    // 0..383999, 4 elements each
  if (f2 == 0) {
    ((uint2*)B)[i] = ((const uint2*)X)[i];
  } else {
    float4 v = ((const float4*)X)[i];
    uint2 o;
    o.x = (u32)f2bf(v.x) | ((u32)f2bf(v.y) << 16);
    o.y = (u32)f2bf(v.z) | ((u32)f2bf(v.w) << 16);
    ((uint2*)B)[i] = o;
  }
}

// ---------------- K2: projection GEMM -> q (scaled), vT ----------------
__global__ __launch_bounds__(256) void k_proj(const u16* __restrict__ xb0,
                                              const u16* __restrict__ xb1,
                                              const u16* __restrict__ WT,
                                              const void* __restrict__ bias,
                                              const u32* __restrict__ flag,
                                              u16* __restrict__ q0, u16* __restrict__ v0t,
                                              u16* __restrict__ q1, u16* __restrict__ v1t) {
  u32 f2 = flag[1];
  int z = blockIdx.z;
  const u16* X = z ? xb1 : xb0;
  u16* Q = z ? q1 : q0;
  u16* V = z ? v1t : v0t;
  int tid = threadIdx.x, w = tid >> 6, lane = tid & 63, quad = lane >> 4, c16 = lane & 15;
  int r0 = blockIdx.x * 16;
  int c  = blockIdx.y * 64 + w * 16 + c16;
  f32x4 acc = {0.f, 0.f, 0.f, 0.f};
#pragma unroll
  for (int k0 = 0; k0 < kC; k0 += 32) {
    short8 a = *(const short8*)(X + (size_t)(r0 + c16) * kC + k0 + quad * 8);
    short8 b = *(const short8*)(WT + (size_t)c * kC + k0 + quad * 8);
    acc = mfma16(a, b, acc);
  }
  float bb = (f2 == 0) ? bf2f(((const u16*)bias)[c]) : ((const float*)bias)[c];
  int row0 = r0 + quad * 4;              // group of 4 rows, never crosses n (3000 % 4 == 0)
  int n = (row0 >= kL) ? 1 : 0;
  int t0 = row0 - n * kL;
  if (c < kH) {                          // qk half (scaled)
    int ff = c >> 5, d = c & 31;
    u16* qp = Q + ((size_t)(n * kFC + ff) * kTP + t0) * kD + d;
#pragma unroll
    for (int r = 0; r < 4; ++r) qp[(size_t)r * kD] = f2bf((acc[r] + bb) * kQSC);
  } else {                               // v half -> transposed [d][t], 4 consecutive t packed
    int cc = c - kH;
    int ff = cc >> 5, d = cc & 31;
    uint2 o;
    o.x = (u32)f2bf(acc[0] + bb) | ((u32)f2bf(acc[1] + bb) << 16);
    o.y = (u32)f2bf(acc[2] + bb) | ((u32)f2bf(acc[3] + bb) << 16);
    *(uint2*)(V + ((size_t)(n * kFC + ff) * kD + d) * kTP + t0) = o;
  }
}

// ---------------- K3: bidirectional flash attention, LDS-free staging ----------------
__global__ __launch_bounds__(256) void k_flash(const u16* __restrict__ q0,
                                               const u16* __restrict__ q1,
                                               const u16* __restrict__ v0t,
                                               const u16* __restrict__ v1t,
                                               const u64* __restrict__ mkb,
                                               const u64* __restrict__ mkbt,
                                               u16* __restrict__ m0h, u16* __restrict__ m1h) {
  const int z = blockIdx.z;
  const u16* QA = z ? q1 : q0;   // output-row side
  const u16* QB = z ? q0 : q1;   // swept side
  const u16* VT = z ? v0t : v1t; // values, [d][t]
  const u64* MB = z ? mkbt : mkb;
  u16* MO = z ? m1h : m0h;

  const int nf = blockIdx.y, n = nf >> 3, f = nf & 7;
  const int tid = threadIdx.x, w = tid >> 6, lane = tid & 63;
  const int quad = lane >> 4, c16 = lane & 15;

  __shared__ u16 ldsP[4][32 * kPS];
  u16* Pl = ldsP[w];

  const u16* qa = QA + (size_t)(n * kFC + f) * kTP * kD;
  const u16* qb = QB + (size_t)(n * kFC + f) * kTP * kD;
  const u16* vt = VT + (size_t)(n * kFC + f) * kD * kTP;
  const u64* mb = MB + (size_t)n * kTP * kMW;

  const int l0 = blockIdx.x * 128, lw = l0 + w * 32;
  int ra0 = lw + c16;      if (ra0 > kTP - 1) ra0 = kTP - 1;
  int ra1 = lw + 16 + c16; if (ra1 > kTP - 1) ra1 = kTP - 1;
  short8 af0 = *(const short8*)(qa + (size_t)ra0 * kD + quad * 8);
  short8 af1 = *(const short8*)(qa + (size_t)ra1 * kD + quad * 8);
  short8 bones;
#pragma unroll
  for (int i = 0; i < 8; ++i) bones[i] = (short)0x3F80;  // bf16 1.0

  f32x4 acc00 = {0.f,0.f,0.f,0.f}, acc01 = acc00, acc10 = acc00, acc11 = acc00;
  f32x4 accs0 = acc00, accs1 = acc00;

  const u64* mp0 = mb + (size_t)ra0 * kMW;
  const u64* mp1 = mb + (size_t)ra1 * kMW;
  const int shb = quad * 4;

  for (int j0 = 0; j0 < kTP; j0 += 64) {
    u64 mw0 = mp0[j0 >> 6], mw1 = mp1[j0 >> 6];
    u32 h0[2] = {(u32)mw0, (u32)(mw0 >> 32)};
    u32 h1[2] = {(u32)mw1, (u32)(mw1 >> 32)};
#pragma unroll
    for (int t = 0; t < 4; ++t) {
      short8 aq = *(const short8*)(qb + (size_t)(j0 + t * 16 + c16) * kD + quad * 8);
      f32x4 zz = {0.f,0.f,0.f,0.f};
      f32x4 s0 = mfma16(aq, af0, zz);     // C[row=s(quad*4+r)][col=l(c16)]
      f32x4 s1 = mfma16(aq, af1, zz);
      const u32 ha = h0[t >> 1], hb = h1[t >> 1];
      const int base = (t & 1) * 16 + shb;
      float p00 = ((ha >> (base + 0)) & 1) ? __builtin_amdgcn_exp2f(s0[0]) : 0.f;
      float p01 = ((ha >> (base + 1)) & 1) ? __builtin_amdgcn_exp2f(s0[1]) : 0.f;
      float p02 = ((ha >> (base + 2)) & 1) ? __builtin_amdgcn_exp2f(s0[2]) : 0.f;
      float p03 = ((ha >> (base + 3)) & 1) ? __builtin_amdgcn_exp2f(s0[3]) : 0.f;
      float p10 = ((hb >> (base + 0)) & 1) ? __builtin_amdgcn_exp2f(s1[0]) : 0.f;
      float p11 = ((hb >> (base + 1)) & 1) ? __builtin_amdgcn_exp2f(s1[1]) : 0.f;
      float p12 = ((hb >> (base + 2)) & 1) ? __builtin_amdgcn_exp2f(s1[2]) : 0.f;
      float p13 = ((hb >> (base + 3)) & 1) ? __builtin_amdgcn_exp2f(s1[3]) : 0.f;
      uint2 w0; w0.x = pk2(p00, p01); w0.y = pk2(p02, p03);
      uint2 w1; w1.x = pk2(p10, p11); w1.y = pk2(p12, p13);
      *(uint2*)(Pl + (size_t)c16 * kPS + t * 16 + shb)        = w0;  // P rows [0,16)
      *(uint2*)(Pl + (size_t)(16 + c16) * kPS + t * 16 + shb) = w1;  // P rows [16,32)
    }
#pragma unroll
    for (int sub = 0; sub < 2; ++sub) {
      const u16* vb = vt + (size_t)c16 * kTP + j0 + sub * 32 + quad * 8;
      short8 bv0 = *(const short8*)(vb);
      short8 bv1 = *(const short8*)(vb + (size_t)16 * kTP);
      short8 ap0 = *(const short8*)(Pl + (size_t)c16 * kPS + sub * 32 + quad * 8);
      short8 ap1 = *(const short8*)(Pl + (size_t)(16 + c16) * kPS + sub * 32 + quad * 8);
      acc00 = mfma16(ap0, bv0, acc00);
      acc01 = mfma16(ap0, bv1, acc01);
      accs0 = mfma16(ap0, bones, accs0);
      acc10 = mfma16(ap1, bv0, acc10);
      acc11 = mfma16(ap1, bv1, acc11);
      accs1 = mfma16(ap1, bones, accs1);
    }
  }

#pragma unroll
  for (int r = 0; r < 4; ++r) {
    float ls0 = accs0[r];
    float rd0 = (ls0 > 0.f) ? (1.f / ls0) : 0.f;
    int lrow0 = lw + quad * 4 + r;
    if (lrow0 < kL) {
      size_t basep = ((size_t)n * kTP + lrow0) * kH + f * kD;
      MO[basep + c16]      = f2bf(acc00[r] * rd0);
      MO[basep + 16 + c16] = f2bf(acc01[r] * rd0);
    }
    float ls1 = accs1[r];
    float rd1 = (ls1 > 0.f) ? (1.f / ls1) : 0.f;
    int lrow1 = lw + 16 + quad * 4 + r;
    if (lrow1 < kL) {
      size_t basep = ((size_t)n * kTP + lrow1) * kH + f * kD;
      MO[basep + c16]      = f2bf(acc10[r] * rd1);
      MO[basep + 16 + c16] = f2bf(acc11[r] * rd1);
    }
  }
}

// ---------------- K5: merge GEMM + bias -> output ----------------
__global__ __launch_bounds__(256) void k_merge(const u16* __restrict__ m0h,
                                               const u16* __restrict__ m1h,
                                               const u16* __restrict__ WmT,
                                               const void* __restrict__ bias,
                                               const u32* __restrict__ flag,
                                               void* __restrict__ out) {
  u32 f2 = flag[1];
  int z = blockIdx.z;
  const u16* A = z ? m1h : m0h;
  int tid = threadIdx.x, w = tid >> 6, lane = tid & 63, quad = lane >> 4, c16 = lane & 15;
  int r0 = blockIdx.x * 16;                     // rows flat over [n][TP], 0..6015
  int c  = blockIdx.y * 64 + w * 16 + c16;      // 0..255
  f32x4 acc = {0.f,0.f,0.f,0.f};
#pragma unroll
  for (int k0 = 0; k0 < kH; k0 += 32) {
    short8 a = *(const short8*)(A + (size_t)(r0 + c16) * kH + k0 + quad * 8);
    short8 b = *(const short8*)(WmT + (size_t)c * kH + k0 + quad * 8);
    acc = mfma16(a, b, acc);
  }
  float bb = (f2 == 0) ? bf2f(((const u16*)bias)[c]) : ((const float*)bias)[c];
  size_t obase = (size_t)z * ((size_t)kNB * kL * kC);
#pragma unroll
  for (int r = 0; r < 4; ++r) {
    int row = r0 + quad * 4 + r;
    int n = (row >= kTP) ? 1 : 0;
    int t = row - n * kTP;
    if (t < kL) {
      size_t oi = obase + ((size_t)n * kL + t) * kC + c;
      float v = acc[r] + bb;
      if (f2 == 0) ((u16*)out)[oi] = f2bf(v);
      else         ((float*)out)[oi] = v;
    }
  }
}

// ---------------- host ----------------
extern "C" void kernel_launch(void* const* d_in, const int* in_sizes, int n_in,
                              void* d_out, int out_size, void* d_ws, size_t ws_size,
                              hipStream_t stream) {
  (void)in_sizes; (void)n_in; (void)out_size; (void)ws_size;
  u8* ws = (u8*)d_ws;
  u32* flag = (u32*)ws;
  u16* q0  = (u16*)(ws + OFF_Q0);
  u16* q1  = (u16*)(ws + OFF_Q1);
  u16* v0t = (u16*)(ws + OFF_V0);
  u16* v1t = (u16*)(ws + OFF_V1);
  u16* m0h = (u16*)(ws + OFF_M0);
  u16* m1h = (u16*)(ws + OFF_M1);
  u16* WT  = (u16*)(ws + OFF_WT);
  u16* WmT = (u16*)(ws + OFF_WM);
  u16* xb0 = (u16*)(ws + OFF_X0);
  u16* xb1 = (u16*)(ws + OFF_X1);
  u64* mkb  = (u64*)(ws + OFF_MKB);
  u64* mkbt = (u64*)(ws + OFF_MKBT);

  const void* x0 = d_in[0];
  const void* x1 = d_in[1];
  const void* mraw = d_in[2];
  const void* Wp = d_in[3];
  const void* bp = d_in[4];
  const void* Wm = d_in[5];
  const void* bm = d_in[6];

  k_detect<<<1, 256, 0, stream>>>((const u8*)mraw, (const u8*)x0, flag);
  k_masknorm<<<dim3(47, 47, 2), 256, 0, stream>>>(mraw, flag, mkb, mkbt);
  k_wtrans<<<dim3(2 * kH + kC), 256, 0, stream>>>(Wp, Wm, flag, WT, WmT);
  k_cvtx<<<dim3(1500, 2), 256, 0, stream>>>(x0, x1, flag, xb0, xb1);
  k_proj<<<dim3(375, 8, 2), 256, 0, stream>>>(xb0, xb1, WT, bp, flag, q0, v0t, q1, v1t);
  k_flash<<<dim3(24, 16, 2), 256, 0, stream>>>(q0, q1, v0t, v1t, mkb, mkbt, m0h, m1h);
  k_merge<<<dim3(376, 4, 2), 256, 0, stream>>>(m0h, m1h, WmT, bm, flag, d_out);
}